// Round 8
// baseline (58.324 us; speedup 1.0000x reference)
//
#include <hip/hip_runtime.h>

#define NB 512
#define NATOMS 1024
#define NG 256
#define NL 8
#define NK 128

#define KBT 0.59616123f            // 0.0019872041 * 300
#define ALPHA_C 10.0f
#define LN2 0.6931471805599453f
#define LOG2E 1.4426950408889634f
#define INV2BW2 22.222221f         // 1/(2*0.15^2)
#define SCALE2 (INV2BW2 * LOG2E)   // log2-domain scale
#define LOG_NORM (-1.0170649f)     // log(128) + 3*log(2*pi*BW^2)

#define WL_CAP 2048                // max active (g,l) pairs = NG*NL
#define FILL_BLOCKS 128            // 128*256*16B = 512 KiB = NG*NB*4B exactly

__device__ __forceinline__ float fexp2(float x) { return __builtin_amdgcn_exp2f(x); }
__device__ __forceinline__ float flog2(float x) { return __builtin_amdgcn_logf(x); }

// monotone float<->uint key (unsigned order == float order), for atomicMin
__device__ __forceinline__ unsigned fkey(float f) {
  unsigned u = __float_as_uint(f);
  return (u & 0x80000000u) ? ~u : (u | 0x80000000u);
}
__device__ __forceinline__ float funkey(unsigned k) {
  unsigned u = (k & 0x80000000u) ? (k ^ 0x80000000u) : ~k;
  return __uint_as_float(u);
}

__device__ __forceinline__ float wred_min(float v) {
#pragma unroll
  for (int m = 32; m >= 1; m >>= 1) v = fminf(v, __shfl_xor(v, m, 64));
  return v;
}
__device__ __forceinline__ float wred_sum(float v) {
#pragma unroll
  for (int m = 32; m >= 1; m >>= 1) v += __shfl_xor(v, m, 64);
  return v;
}

// Grid = 1 + FILL_BLOCKS.  Block 0: prefix-sum nl over the 256 groups ->
// packed worklist of active (g,l) pairs (wl[WL_CAP] = count).  Blocks
// 1..FILL_BLOCKS: fill gmin_u with 0xFFFFFFFF (full 512 KiB).
__global__ __launch_bounds__(256) void build_worklist(
    const int* __restrict__ gsizes, int* __restrict__ wl,
    uint4* __restrict__ gmin_u4) {
  const int t = threadIdx.x;
  if (blockIdx.x != 0) {
    const unsigned F = 0xFFFFFFFFu;
    gmin_u4[(blockIdx.x - 1) * 256 + t] = make_uint4(F, F, F, F);
    return;
  }
  const int lane = t & 63, wid = t >> 6;
  int gs = gsizes[t];
  int nl = gs < 1 ? 1 : (gs > NL ? NL : gs);
  int x = nl;                       // inclusive scan within wave
#pragma unroll
  for (int m = 1; m < 64; m <<= 1) {
    int y = __shfl_up(x, m, 64);
    if (lane >= m) x += y;
  }
  __shared__ int wsum[4];
  if (lane == 63) wsum[wid] = x;
  __syncthreads();
  int off = 0;
  for (int i = 0; i < wid; ++i) off += wsum[i];
  int inc = off + x, exc = inc - nl;
  for (int j = 0; j < nl; ++j) wl[exc + j] = (t << 3) | j;
  if (t == 255) wl[WL_CAP] = inc;   // total active pairs
}

// positions[b][a][c] -> pT[a][c][b]: makes stage1's per-atom gather fully
// coalesced (lane index == b).  Reads coalesced float4; scattered dword
// STORES (stores don't stall the wave).  Runs once, ~3-5 us.
__global__ __launch_bounds__(256) void transpose_pos(
    const float* __restrict__ positions, float* __restrict__ pT) {
  const int b = blockIdx.x;
  const int t = threadIdx.x;
  const float4* src = reinterpret_cast<const float4*>(
      positions + (size_t)b * NATOMS * 3);
  float4 v0 = src[t * 3 + 0], v1 = src[t * 3 + 1], v2 = src[t * 3 + 2];
  float x[4], y[4], z[4];
  x[0] = v0.x; y[0] = v0.y; z[0] = v0.z;
  x[1] = v0.w; y[1] = v1.x; z[1] = v1.y;
  x[2] = v1.z; y[2] = v1.w; z[2] = v2.x;
  x[3] = v2.y; y[3] = v2.z; z[3] = v2.w;
  const int a0 = t << 2;
#pragma unroll
  for (int j = 0; j < 4; ++j) {
    float* dst = pT + (size_t)(a0 + j) * 3 * NB;
    dst[b] = x[j];
    dst[NB + b] = y[j];
    dst[2 * NB + b] = z[j];
  }
}

// Block = one (worklist entry, b-half) [round-6 structure: 7360 waves].
// Thread t owns b = bq*256 + t; K=128 logsumexp serial in registers,
// 4 online chains, 4-k merge groups, log2 domain.  Position loads now
// coalesced via pT.
__global__ __launch_bounds__(256) void stage1_kernel(
    const float* __restrict__ pT, const float* __restrict__ kde,
    const float* __restrict__ weight, const float* __restrict__ offs,
    const int* __restrict__ atom_idxs, const int* __restrict__ wl,
    unsigned* __restrict__ gmin_u) {
  const int w = blockIdx.x >> 1;
  const int bq = blockIdx.x & 1;
  const int count = wl[WL_CAP];
  if (w >= count) return;                 // contiguous inactive tail
  const int e = wl[w];
  const int g = e >> 3, l = e & 7;
  const int gl = g * NL + l;

  __shared__ __align__(16) float tab[NK][8];   // [mu'0..5, h, pad] (log2 dom.)

  const int t = threadIdx.x;
  const float* kb = kde + (size_t)gl * NK * 6;
  if (t < NK) {
    const float* mp = kb + t * 6;
    float m0 = mp[0], m1 = mp[1], m2 = mp[2], m3 = mp[3], m4 = mp[4], m5 = mp[5];
    float mu2 = m0 * m0 + m1 * m1 + m2 * m2 + m3 * m3 + m4 * m4 + m5 * m5;
    const float cf = 2.0f * SCALE2;
    float4 lo = make_float4(m0 * cf, m1 * cf, m2 * cf, m3 * cf);
    float4 hi = make_float4(m4 * cf, m5 * cf, -mu2 * SCALE2, 0.0f);
    *reinterpret_cast<float4*>(&tab[t][0]) = lo;
    *reinterpret_cast<float4*>(&tab[t][4]) = hi;
  }
  __syncthreads();

  const int b = bq * 256 + t;
  const int4 idx = *reinterpret_cast<const int4*>(atom_idxs + (gl << 2));
  const int ids[4] = {idx.x, idx.y, idx.z, idx.w};
  float ax[4], ay[4], az[4];
#pragma unroll
  for (int j = 0; j < 4; ++j) {
    const float* base = pT + (size_t)ids[j] * 3 * NB;   // coalesced: lane==b
    ax[j] = base[b];
    ay[j] = base[NB + b];
    az[j] = base[2 * NB + b];
  }
  const int PI_[6] = {0, 0, 0, 1, 1, 2};
  const int PJ_[6] = {1, 2, 3, 2, 3, 3};
  float d[6]; float x2 = 0.0f;
#pragma unroll
  for (int q = 0; q < 6; ++q) {
    float dx = ax[PI_[q]] - ax[PJ_[q]];
    float dy = ay[PI_[q]] - ay[PJ_[q]];
    float dz = az[PI_[q]] - az[PJ_[q]];
    float dd = dx * dx + dy * dy + dz * dz + 1e-12f;
    d[q] = sqrtf(dd);
    x2 += d[q] * d[q];
  }
  const float c2 = -x2 * SCALE2;     // constant over k (log2 domain)

  // 4 independent online-LSE chains; each step merges a group of 4 k's.
  float m_[4] = {-1e30f, -1e30f, -1e30f, -1e30f};
  float s_[4] = {0.0f, 0.0f, 0.0f, 0.0f};
  for (int k0 = 0; k0 < NK; k0 += 16) {
#pragma unroll
    for (int j = 0; j < 4; ++j) {
      const int kk = k0 + (j << 2);
      float v[4];
#pragma unroll
      for (int i = 0; i < 4; ++i) {
        const float4* r = reinterpret_cast<const float4*>(&tab[kk + i][0]);
        float4 A = r[0], Bv = r[1];
        float vv = Bv.z;
        vv = fmaf(A.x, d[0], vv);
        vv = fmaf(A.y, d[1], vv);
        vv = fmaf(A.z, d[2], vv);
        vv = fmaf(A.w, d[3], vv);
        vv = fmaf(Bv.x, d[4], vv);
        vv = fmaf(Bv.y, d[5], vv);
        v[i] = vv;
      }
      float gm = fmaxf(fmaxf(v[0], v[1]), fmaxf(v[2], v[3]));
      float p = fexp2(v[0] - gm) + fexp2(v[1] - gm)
              + fexp2(v[2] - gm) + fexp2(v[3] - gm);
      float nm = fmaxf(m_[j], gm);
      s_[j] = fmaf(s_[j], fexp2(m_[j] - nm), p * fexp2(gm - nm));
      m_[j] = nm;
    }
  }
  float M = fmaxf(fmaxf(m_[0], m_[1]), fmaxf(m_[2], m_[3]));
  float S = s_[0] * fexp2(m_[0] - M) + s_[1] * fexp2(m_[1] - M)
          + s_[2] * fexp2(m_[2] - M) + s_[3] * fexp2(m_[3] - M);

  float lse2 = c2 + M + flog2(S);            // log2(sum_k exp(v_k))
  float logP = lse2 * LN2 - LOG_NORM;
  float scaled = -KBT * logP * weight[gl] + offs[gl];
  atomicMin(&gmin_u[g * NB + b], fkey(scaled));
}

// One block per b: min over g, then logsumexp(-ALPHA*gmin) over g.
__global__ __launch_bounds__(256) void stage2_kernel(
    const unsigned* __restrict__ gmin_u, float* __restrict__ out) {
  const int b = blockIdx.x;
  const int t = threadIdx.x;
  const int lane = t & 63;
  const int wid = t >> 6;
  float v = funkey(gmin_u[t * NB + b]);
  __shared__ float sm[4], ss[4];
  float m = wred_min(v);
  if (lane == 0) sm[wid] = m;
  __syncthreads();
  float M = fminf(fminf(sm[0], sm[1]), fminf(sm[2], sm[3]));
  float e = fexp2(-ALPHA_C * LOG2E * (v - M));
  float s = wred_sum(e);
  if (lane == 0) ss[wid] = s;
  __syncthreads();
  if (t == 0) {
    float S = ss[0] + ss[1] + ss[2] + ss[3];
    out[b] = M - flog2(S) * LN2 / ALPHA_C;
  }
}

extern "C" void kernel_launch(void* const* d_in, const int* in_sizes, int n_in,
                              void* d_out, int out_size, void* d_ws, size_t ws_size,
                              hipStream_t stream) {
  const float* positions = (const float*)d_in[0];
  const float* kde       = (const float*)d_in[1];
  const float* weight    = (const float*)d_in[2];
  const float* offs      = (const float*)d_in[3];
  const int*   atom_idxs = (const int*)d_in[4];
  const int*   gsizes    = (const int*)d_in[5];
  float* out = (float*)d_out;

  unsigned* gmin_u = (unsigned*)d_ws;                     // 512 KiB
  int* wl = (int*)d_ws + (size_t)NG * NB;                 // ~8 KiB
  float* pT = (float*)((char*)d_ws + (1 << 20));          // 6 MiB at +1 MiB

  build_worklist<<<dim3(1 + FILL_BLOCKS), dim3(256), 0, stream>>>(
      gsizes, wl, (uint4*)gmin_u);
  transpose_pos<<<dim3(NB), dim3(256), 0, stream>>>(positions, pT);
  stage1_kernel<<<dim3(WL_CAP * 2), dim3(256), 0, stream>>>(
      pT, kde, weight, offs, atom_idxs, wl, gmin_u);
  stage2_kernel<<<dim3(NB), dim3(256), 0, stream>>>(gmin_u, out);
}

// Round 9
// 55.584 us; speedup vs baseline: 1.0493x; 1.0493x over previous
//
#include <hip/hip_runtime.h>

#define NB 512
#define NATOMS 1024
#define NG 256
#define NL 8
#define NK 128

#define KBT 0.59616123f            // 0.0019872041 * 300
#define ALPHA_C 10.0f
#define LN2 0.6931471805599453f
#define LOG2E 1.4426950408889634f
#define INV2BW2 22.222221f         // 1/(2*0.15^2)
#define SCALE2 (INV2BW2 * LOG2E)   // log2-domain scale
#define LOG_NORM (-1.0170649f)     // log(128) + 3*log(2*pi*BW^2)

#define WL_CAP 2048                // max (g,l) pairs = NG*NL
#define FILL_BLOCKS 128            // 128*256*16B = 512 KiB = NG*NB*4B exactly

__device__ __forceinline__ float fexp2(float x) { return __builtin_amdgcn_exp2f(x); }
__device__ __forceinline__ float flog2(float x) { return __builtin_amdgcn_logf(x); }

// monotone float<->uint key (unsigned order == float order), for atomicMin
__device__ __forceinline__ unsigned fkey(float f) {
  unsigned u = __float_as_uint(f);
  return (u & 0x80000000u) ? ~u : (u | 0x80000000u);
}
__device__ __forceinline__ float funkey(unsigned k) {
  unsigned u = (k & 0x80000000u) ? (k ^ 0x80000000u) : ~k;
  return __uint_as_float(u);
}

__device__ __forceinline__ float wred_min(float v) {
#pragma unroll
  for (int m = 32; m >= 1; m >>= 1) v = fminf(v, __shfl_xor(v, m, 64));
  return v;
}
__device__ __forceinline__ float wred_sum(float v) {
#pragma unroll
  for (int m = 32; m >= 1; m >>= 1) v += __shfl_xor(v, m, 64);
  return v;
}

// Precompute the transformed KDE table for ALL 2048 (g,l) entries:
// tabG[gl][k][8] = {mu0*cf .. mu5*cf, -mu2*SCALE2, 0}.  Coalesced r/w, ~3us.
__global__ __launch_bounds__(128) void prep_tab(
    const float* __restrict__ kde, float* __restrict__ tabG) {
  const int gl = blockIdx.x;
  const int k = threadIdx.x;
  const float* mp = kde + ((size_t)gl * NK + k) * 6;
  float m0 = mp[0], m1 = mp[1], m2 = mp[2], m3 = mp[3], m4 = mp[4], m5 = mp[5];
  float mu2 = m0 * m0 + m1 * m1 + m2 * m2 + m3 * m3 + m4 * m4 + m5 * m5;
  const float cf = 2.0f * SCALE2;
  float4* dst = reinterpret_cast<float4*>(tabG + ((size_t)gl * NK + k) * 8);
  dst[0] = make_float4(m0 * cf, m1 * cf, m2 * cf, m3 * cf);
  dst[1] = make_float4(m4 * cf, m5 * cf, -mu2 * SCALE2, 0.0f);
}

// Grid = 1 + FILL_BLOCKS.  Block 0: prefix-sum nl over the 256 groups ->
// packed worklist of active (g,l) pairs (wl[WL_CAP] = count).  Blocks
// 1..FILL_BLOCKS: fill gmin_u with 0xFFFFFFFF (full 512 KiB).
__global__ __launch_bounds__(256) void build_worklist(
    const int* __restrict__ gsizes, int* __restrict__ wl,
    uint4* __restrict__ gmin_u4) {
  const int t = threadIdx.x;
  if (blockIdx.x != 0) {
    const unsigned F = 0xFFFFFFFFu;
    gmin_u4[(blockIdx.x - 1) * 256 + t] = make_uint4(F, F, F, F);
    return;
  }
  const int lane = t & 63, wid = t >> 6;
  int gs = gsizes[t];
  int nl = gs < 1 ? 1 : (gs > NL ? NL : gs);
  int x = nl;                       // inclusive scan within wave
#pragma unroll
  for (int m = 1; m < 64; m <<= 1) {
    int y = __shfl_up(x, m, 64);
    if (lane >= m) x += y;
  }
  __shared__ int wsum[4];
  if (lane == 63) wsum[wid] = x;
  __syncthreads();
  int off = 0;
  for (int i = 0; i < wid; ++i) off += wsum[i];
  int inc = off + x, exc = inc - nl;
  for (int j = 0; j < nl; ++j) wl[exc + j] = (t << 3) | j;   // entry == gl
  if (t == 255) wl[WL_CAP] = inc;   // total active pairs
}

// Block = one (worklist entry, b-half); thread t owns b = bq*256 + t.
// NO LDS: the block-uniform table is read via a readfirstlane-forced
// scalar pointer -> s_load through the SMEM pipe (round-8 analysis: the
// ds_read_b128 stream was the 37us wall; SMEM+SGPR operands bypass it).
// K=128 logsumexp: 4 online chains, 4-k merge groups, log2 domain.
__global__ __launch_bounds__(256) void stage1_kernel(
    const float* __restrict__ positions, const float* __restrict__ tabG,
    const float* __restrict__ weight, const float* __restrict__ offs,
    const int* __restrict__ atom_idxs, const int* __restrict__ wl,
    unsigned* __restrict__ gmin_u) {
  const int w = blockIdx.x >> 1;
  const int bq = blockIdx.x & 1;
  const int count = wl[WL_CAP];
  if (w >= count) return;                 // contiguous inactive tail
  const int gl = __builtin_amdgcn_readfirstlane(wl[w]);   // force SGPR
  const int g = gl >> 3;

  const float4* tb = reinterpret_cast<const float4*>(
      tabG + (size_t)gl * NK * 8);        // uniform (SGPR) base

  const int t = threadIdx.x;
  const int b = bq * 256 + t;
  const int4 idx = *reinterpret_cast<const int4*>(atom_idxs + (gl << 2));
  const int ids[4] = {idx.x, idx.y, idx.z, idx.w};
  const float* pb = positions + (size_t)b * NATOMS * 3;
  float ax[4], ay[4], az[4];
#pragma unroll
  for (int j = 0; j < 4; ++j) {
    const float3 p = *reinterpret_cast<const float3*>(pb + ids[j] * 3);
    ax[j] = p.x; ay[j] = p.y; az[j] = p.z;
  }
  const int PI_[6] = {0, 0, 0, 1, 1, 2};
  const int PJ_[6] = {1, 2, 3, 2, 3, 3};
  float d[6]; float x2 = 0.0f;
#pragma unroll
  for (int q = 0; q < 6; ++q) {
    float dx = ax[PI_[q]] - ax[PJ_[q]];
    float dy = ay[PI_[q]] - ay[PJ_[q]];
    float dz = az[PI_[q]] - az[PJ_[q]];
    float dd = dx * dx + dy * dy + dz * dz + 1e-12f;
    d[q] = sqrtf(dd);
    x2 += d[q] * d[q];
  }
  const float c2 = -x2 * SCALE2;     // constant over k (log2 domain)

  // 4 independent online-LSE chains; each step merges a group of 4 k's.
  float m_[4] = {-1e30f, -1e30f, -1e30f, -1e30f};
  float s_[4] = {0.0f, 0.0f, 0.0f, 0.0f};
  for (int k0 = 0; k0 < NK; k0 += 16) {
#pragma unroll
    for (int j = 0; j < 4; ++j) {
      const int kk = k0 + (j << 2);
      float v[4];
#pragma unroll
      for (int i = 0; i < 4; ++i) {
        float4 A = tb[(kk + i) * 2];      // uniform -> s_load_dwordx4
        float4 Bv = tb[(kk + i) * 2 + 1];
        float vv = Bv.z;
        vv = fmaf(A.x, d[0], vv);
        vv = fmaf(A.y, d[1], vv);
        vv = fmaf(A.z, d[2], vv);
        vv = fmaf(A.w, d[3], vv);
        vv = fmaf(Bv.x, d[4], vv);
        vv = fmaf(Bv.y, d[5], vv);
        v[i] = vv;
      }
      float gm = fmaxf(fmaxf(v[0], v[1]), fmaxf(v[2], v[3]));
      float p = fexp2(v[0] - gm) + fexp2(v[1] - gm)
              + fexp2(v[2] - gm) + fexp2(v[3] - gm);
      float nm = fmaxf(m_[j], gm);
      s_[j] = fmaf(s_[j], fexp2(m_[j] - nm), p * fexp2(gm - nm));
      m_[j] = nm;
    }
  }
  float M = fmaxf(fmaxf(m_[0], m_[1]), fmaxf(m_[2], m_[3]));
  float S = s_[0] * fexp2(m_[0] - M) + s_[1] * fexp2(m_[1] - M)
          + s_[2] * fexp2(m_[2] - M) + s_[3] * fexp2(m_[3] - M);

  float lse2 = c2 + M + flog2(S);            // log2(sum_k exp(v_k))
  float logP = lse2 * LN2 - LOG_NORM;
  float scaled = -KBT * logP * weight[gl] + offs[gl];
  atomicMin(&gmin_u[g * NB + b], fkey(scaled));   // coalesced over lanes
}

// One block per b: min over g, then logsumexp(-ALPHA*gmin) over g.
__global__ __launch_bounds__(256) void stage2_kernel(
    const unsigned* __restrict__ gmin_u, float* __restrict__ out) {
  const int b = blockIdx.x;
  const int t = threadIdx.x;
  const int lane = t & 63;
  const int wid = t >> 6;
  float v = funkey(gmin_u[t * NB + b]);
  __shared__ float sm[4], ss[4];
  float m = wred_min(v);
  if (lane == 0) sm[wid] = m;
  __syncthreads();
  float M = fminf(fminf(sm[0], sm[1]), fminf(sm[2], sm[3]));
  float e = fexp2(-ALPHA_C * LOG2E * (v - M));
  float s = wred_sum(e);
  if (lane == 0) ss[wid] = s;
  __syncthreads();
  if (t == 0) {
    float S = ss[0] + ss[1] + ss[2] + ss[3];
    out[b] = M - flog2(S) * LN2 / ALPHA_C;
  }
}

extern "C" void kernel_launch(void* const* d_in, const int* in_sizes, int n_in,
                              void* d_out, int out_size, void* d_ws, size_t ws_size,
                              hipStream_t stream) {
  const float* positions = (const float*)d_in[0];
  const float* kde       = (const float*)d_in[1];
  const float* weight    = (const float*)d_in[2];
  const float* offs      = (const float*)d_in[3];
  const int*   atom_idxs = (const int*)d_in[4];
  const int*   gsizes    = (const int*)d_in[5];
  float* out = (float*)d_out;

  unsigned* gmin_u = (unsigned*)d_ws;                     // 512 KiB @ 0
  int* wl = (int*)d_ws + (size_t)NG * NB;                 // ~8 KiB @ 512 KiB
  float* tabG = (float*)((char*)d_ws + (1 << 20));        // 8 MiB @ 1 MiB

  prep_tab<<<dim3(WL_CAP), dim3(128), 0, stream>>>(kde, tabG);
  build_worklist<<<dim3(1 + FILL_BLOCKS), dim3(256), 0, stream>>>(
      gsizes, wl, (uint4*)gmin_u);
  stage1_kernel<<<dim3(WL_CAP * 2), dim3(256), 0, stream>>>(
      positions, tabG, weight, offs, atom_idxs, wl, gmin_u);
  stage2_kernel<<<dim3(NB), dim3(256), 0, stream>>>(gmin_u, out);
}